// Round 1
// baseline (609.398 us; speedup 1.0000x reference)
//
#include <hip/hip_runtime.h>
#include <hip/hip_bf16.h>

// MHA: out = softmax((x@Wq^T)(x@Wk^T)^T / sqrt(D)) (x@Wv^T) @ Wo^T
// B=2, S=2048, E=1024, H=16, D=64.

typedef __attribute__((ext_vector_type(8))) short short8;
typedef __attribute__((ext_vector_type(4))) float f32x4;

#define MFMA16(a, b, c) __builtin_amdgcn_mfma_f32_16x16x32_bf16(a, b, c, 0, 0, 0)

static constexpr int B = 2;
static constexpr int S = 2048;
static constexpr int E = 1024;
static constexpr int H = 16;
static constexpr int D = 64;
static constexpr int M = B * S;          // 4096 rows in projection GEMMs
static constexpr size_t NE = (size_t)M * E;   // activation elements
static constexpr size_t NW = (size_t)E * E;   // weight elements

// round-to-nearest-even fp32 -> bf16 (bit pattern as ushort)
static __device__ __forceinline__ unsigned short f2bf(float x) {
  unsigned int u = __float_as_uint(x);
  unsigned int r = (u + 0x7FFFu + ((u >> 16) & 1u)) >> 16;
  return (unsigned short)r;
}

// ---------------- fp32 -> bf16 conversion (vectorized) ----------------
__global__ void cvt_f32_bf16_kernel(const float* __restrict__ src,
                                    unsigned short* __restrict__ dst, int n4) {
  for (int i = blockIdx.x * blockDim.x + threadIdx.x; i < n4;
       i += gridDim.x * blockDim.x) {
    float4 v = reinterpret_cast<const float4*>(src)[i];
    ushort4 o;
    o.x = f2bf(v.x); o.y = f2bf(v.y); o.z = f2bf(v.z); o.w = f2bf(v.w);
    reinterpret_cast<ushort4*>(dst)[i] = o;
  }
}

// ---------------- projection GEMMs: out = A @ W^T ----------------
// A: [4096][1024] bf16 row-major. W: [1024][1024] bf16 row-major (row = out col).
// which==0: Q -> Qh[B][H][S][D], pre-scaled by 0.125
// which==1: K -> Kh[B][H][S][D]
// which==2: V -> Vt[B][H][D][S]   (transposed for PV fragment loads)
__global__ __launch_bounds__(256) void gemm_proj_kernel(
    const unsigned short* __restrict__ Aq, const unsigned short* __restrict__ Ak,
    const unsigned short* __restrict__ Av, const unsigned short* __restrict__ Wq,
    const unsigned short* __restrict__ Wk, const unsigned short* __restrict__ Wv,
    unsigned short* __restrict__ Qh, unsigned short* __restrict__ Kh,
    unsigned short* __restrict__ Vt) {
  const int which = blockIdx.z;
  const unsigned short* A = (which == 0) ? Aq : ((which == 1) ? Ak : Av);
  const unsigned short* W = (which == 0) ? Wq : ((which == 1) ? Wk : Wv);

  const int wave = threadIdx.x >> 6;
  const int lane = threadIdx.x & 63;
  const int lr = lane & 15;          // M-row (A) / N-col (B) selector
  const int lk = (lane >> 4) * 8;    // k offset within 32
  const int rbase = (lane >> 4) * 4; // C/D row base
  const int m0 = blockIdx.x * 64 + wave * 16;
  const int n0 = blockIdx.y * 64;

  const f32x4 fz = {0.f, 0.f, 0.f, 0.f};
  f32x4 acc[4];
#pragma unroll
  for (int nt = 0; nt < 4; ++nt) acc[nt] = fz;

  const unsigned short* Arow = A + (size_t)(m0 + lr) * E + lk;
#pragma unroll 4
  for (int kk = 0; kk < E; kk += 32) {
    short8 a = *reinterpret_cast<const short8*>(Arow + kk);
#pragma unroll
    for (int nt = 0; nt < 4; ++nt) {
      short8 b =
          *reinterpret_cast<const short8*>(W + (size_t)(n0 + nt * 16 + lr) * E + kk + lk);
      acc[nt] = MFMA16(a, b, acc[nt]);
    }
  }

#pragma unroll
  for (int nt = 0; nt < 4; ++nt) {
    const int col = n0 + nt * 16 + lr;
    const int h = col >> 6, d = col & 63;
#pragma unroll
    for (int r = 0; r < 4; ++r) {
      const int row = m0 + rbase + r;
      const int b = row >> 11, s = row & (S - 1);
      const float v = acc[nt][r];
      if (which == 0) {
        Qh[(((size_t)b * H + h) * S + s) * D + d] = f2bf(v * 0.125f);
      } else if (which == 1) {
        Kh[(((size_t)b * H + h) * S + s) * D + d] = f2bf(v);
      } else {
        Vt[(((size_t)b * H + h) * D + d) * S + s] = f2bf(v);
      }
    }
  }
}

// ---------------- flash attention ----------------
// grid: (S/64, B*H). 4 waves/block; wave owns 16 q-rows. Online softmax over
// key tiles of 64. Qh pre-scaled by 1/sqrt(D).
__global__ __launch_bounds__(256) void attn_kernel(
    const unsigned short* __restrict__ Qh, const unsigned short* __restrict__ Kh,
    const unsigned short* __restrict__ Vt, unsigned short* __restrict__ Xb) {
  __shared__ __align__(16) unsigned short Plds[4][16][64];

  const int wave = threadIdx.x >> 6;
  const int lane = threadIdx.x & 63;
  const int lr = lane & 15;
  const int lk = (lane >> 4) * 8;
  const int rbase = (lane >> 4) * 4;
  const int bh = blockIdx.y;
  const int q0 = blockIdx.x * 64 + wave * 16;

  const unsigned short* Qp = Qh + ((size_t)bh * S + q0) * D;
  short8 qf0 = *reinterpret_cast<const short8*>(Qp + (size_t)lr * D + lk);
  short8 qf1 = *reinterpret_cast<const short8*>(Qp + (size_t)lr * D + 32 + lk);

  const f32x4 fz = {0.f, 0.f, 0.f, 0.f};
  float mrun[4], lsum[4];
  f32x4 acc[4];
#pragma unroll
  for (int r = 0; r < 4; ++r) { mrun[r] = -3.0e38f; lsum[r] = 0.f; }
#pragma unroll
  for (int dt = 0; dt < 4; ++dt) acc[dt] = fz;

  const unsigned short* Vbase = Vt + (size_t)bh * D * S;

  for (int kt = 0; kt < S; kt += 64) {
    const unsigned short* Kp = Kh + ((size_t)bh * S + kt) * D;
    f32x4 sf[4];
#pragma unroll
    for (int nt = 0; nt < 4; ++nt) {
      const unsigned short* kr = Kp + (size_t)(nt * 16 + lr) * D + lk;
      short8 kf0 = *reinterpret_cast<const short8*>(kr);
      short8 kf1 = *reinterpret_cast<const short8*>(kr + 32);
      f32x4 z = fz;
      z = MFMA16(qf0, kf0, z);
      z = MFMA16(qf1, kf1, z);
      sf[nt] = z;
    }

    float p[4][4];
#pragma unroll
    for (int r = 0; r < 4; ++r) {
      float mx = fmaxf(fmaxf(sf[0][r], sf[1][r]), fmaxf(sf[2][r], sf[3][r]));
      mx = fmaxf(mx, __shfl_xor(mx, 1));
      mx = fmaxf(mx, __shfl_xor(mx, 2));
      mx = fmaxf(mx, __shfl_xor(mx, 4));
      mx = fmaxf(mx, __shfl_xor(mx, 8));
      const float nm = fmaxf(mrun[r], mx);
      const float fac = __expf(mrun[r] - nm);
      mrun[r] = nm;
      float rs = 0.f;
#pragma unroll
      for (int nt = 0; nt < 4; ++nt) {
        p[nt][r] = __expf(sf[nt][r] - nm);
        rs += p[nt][r];
      }
      rs += __shfl_xor(rs, 1);
      rs += __shfl_xor(rs, 2);
      rs += __shfl_xor(rs, 4);
      rs += __shfl_xor(rs, 8);
      lsum[r] = lsum[r] * fac + rs;
#pragma unroll
      for (int dt = 0; dt < 4; ++dt) acc[dt][r] *= fac;
    }

    // C/D layout -> A-fragment layout via LDS (per-wave buffer)
#pragma unroll
    for (int nt = 0; nt < 4; ++nt)
#pragma unroll
      for (int r = 0; r < 4; ++r)
        Plds[wave][rbase + r][nt * 16 + lr] = f2bf(p[nt][r]);
    __syncthreads();
    short8 pa0 = *reinterpret_cast<const short8*>(&Plds[wave][lr][lk]);
    short8 pa1 = *reinterpret_cast<const short8*>(&Plds[wave][lr][32 + lk]);

#pragma unroll
    for (int dt = 0; dt < 4; ++dt) {
      const unsigned short* vr = Vbase + (size_t)(dt * 16 + lr) * S + kt + lk;
      short8 vf0 = *reinterpret_cast<const short8*>(vr);
      short8 vf1 = *reinterpret_cast<const short8*>(vr + 32);
      acc[dt] = MFMA16(pa0, vf0, acc[dt]);
      acc[dt] = MFMA16(pa1, vf1, acc[dt]);
    }
    __syncthreads();
  }

  const int b = bh >> 4, h = bh & (H - 1);
#pragma unroll
  for (int r = 0; r < 4; ++r) {
    const float inv = 1.0f / lsum[r];
    const int row = q0 + rbase + r;
#pragma unroll
    for (int dt = 0; dt < 4; ++dt) {
      Xb[((size_t)b * S + row) * E + h * D + dt * 16 + lr] =
          f2bf(acc[dt][r] * inv);
    }
  }
}

// ---------------- output GEMM: out = X @ Wo^T (fp32 out) ----------------
__global__ __launch_bounds__(256) void gemm_out_kernel(
    const unsigned short* __restrict__ X, const unsigned short* __restrict__ Wo,
    float* __restrict__ out) {
  const int wave = threadIdx.x >> 6;
  const int lane = threadIdx.x & 63;
  const int lr = lane & 15;
  const int lk = (lane >> 4) * 8;
  const int rbase = (lane >> 4) * 4;
  const int m0 = blockIdx.x * 64 + wave * 16;
  const int n0 = blockIdx.y * 64;

  const f32x4 fz = {0.f, 0.f, 0.f, 0.f};
  f32x4 acc[4];
#pragma unroll
  for (int nt = 0; nt < 4; ++nt) acc[nt] = fz;

  const unsigned short* Xrow = X + (size_t)(m0 + lr) * E + lk;
#pragma unroll 4
  for (int kk = 0; kk < E; kk += 32) {
    short8 a = *reinterpret_cast<const short8*>(Xrow + kk);
#pragma unroll
    for (int nt = 0; nt < 4; ++nt) {
      short8 b =
          *reinterpret_cast<const short8*>(Wo + (size_t)(n0 + nt * 16 + lr) * E + kk + lk);
      acc[nt] = MFMA16(a, b, acc[nt]);
    }
  }

#pragma unroll
  for (int nt = 0; nt < 4; ++nt) {
    const int col = n0 + nt * 16 + lr;
#pragma unroll
    for (int r = 0; r < 4; ++r) {
      const int row = m0 + rbase + r;
      out[(size_t)row * E + col] = acc[nt][r];
    }
  }
}

extern "C" void kernel_launch(void* const* d_in, const int* in_sizes, int n_in,
                              void* d_out, int out_size, void* d_ws, size_t ws_size,
                              hipStream_t stream) {
  const float* q_f = (const float*)d_in[0];
  const float* k_f = (const float*)d_in[1];
  const float* v_f = (const float*)d_in[2];
  const float* wq_f = (const float*)d_in[3];
  const float* wk_f = (const float*)d_in[4];
  const float* wv_f = (const float*)d_in[5];
  const float* wo_f = (const float*)d_in[6];

  // workspace layout (bf16 halves): 7*NE + 4*NW elements = 64 MB
  unsigned short* xq = (unsigned short*)d_ws;
  unsigned short* xk = xq + NE;
  unsigned short* xv = xk + NE;
  unsigned short* wq = xv + NE;
  unsigned short* wk = wq + NW;
  unsigned short* wv = wk + NW;
  unsigned short* wo = wv + NW;
  unsigned short* Qh = wo + NW;
  unsigned short* Kh = Qh + NE;
  unsigned short* Vt = Kh + NE;
  unsigned short* Xb = Vt + NE;

  // 1) convert inputs + weights to bf16
  cvt_f32_bf16_kernel<<<2048, 256, 0, stream>>>(q_f, xq, (int)(NE / 4));
  cvt_f32_bf16_kernel<<<2048, 256, 0, stream>>>(k_f, xk, (int)(NE / 4));
  cvt_f32_bf16_kernel<<<2048, 256, 0, stream>>>(v_f, xv, (int)(NE / 4));
  cvt_f32_bf16_kernel<<<512, 256, 0, stream>>>(wq_f, wq, (int)(NW / 4));
  cvt_f32_bf16_kernel<<<512, 256, 0, stream>>>(wk_f, wk, (int)(NW / 4));
  cvt_f32_bf16_kernel<<<512, 256, 0, stream>>>(wv_f, wv, (int)(NW / 4));
  cvt_f32_bf16_kernel<<<512, 256, 0, stream>>>(wo_f, wo, (int)(NW / 4));

  // 2) Q/K/V projections (z selects which)
  gemm_proj_kernel<<<dim3(M / 64, E / 64, 3), 256, 0, stream>>>(
      xq, xk, xv, wq, wk, wv, Qh, Kh, Vt);

  // 3) flash attention
  attn_kernel<<<dim3(S / 64, B * H), 256, 0, stream>>>(Qh, Kh, Vt, Xb);

  // 4) output projection
  gemm_out_kernel<<<dim3(M / 64, E / 64), 256, 0, stream>>>(Xb, wo, (float*)d_out);
}

// Round 2
// 337.760 us; speedup vs baseline: 1.8042x; 1.8042x over previous
//
#include <hip/hip_runtime.h>
#include <hip/hip_bf16.h>

// MHA: out = softmax((x@Wq^T)(x@Wk^T)^T / sqrt(D)) (x@Wv^T) @ Wo^T
// B=2, S=2048, E=1024, H=16, D=64.

typedef __attribute__((ext_vector_type(8))) short short8;
typedef __attribute__((ext_vector_type(4))) float f32x4;

#define MFMA16(a, b, c) __builtin_amdgcn_mfma_f32_16x16x32_bf16(a, b, c, 0, 0, 0)

static constexpr int B = 2;
static constexpr int S = 2048;
static constexpr int E = 1024;
static constexpr int H = 16;
static constexpr int D = 64;
static constexpr int M = B * S;               // 4096 rows in projection GEMMs
static constexpr size_t NE = (size_t)M * E;   // activation elements
static constexpr size_t NW = (size_t)E * E;   // weight elements

// round-to-nearest-even fp32 -> bf16 (bit pattern as ushort)
static __device__ __forceinline__ unsigned short f2bf(float x) {
  unsigned int u = __float_as_uint(x);
  unsigned int r = (u + 0x7FFFu + ((u >> 16) & 1u)) >> 16;
  return (unsigned short)r;
}

// async global -> LDS, 16B per lane. LDS dest = wave-uniform base + lane*16.
static __device__ __forceinline__ void gload_lds16(const unsigned short* g,
                                                   unsigned short* l) {
  __builtin_amdgcn_global_load_lds(
      (const __attribute__((address_space(1))) unsigned int*)g,
      (__attribute__((address_space(3))) unsigned int*)l, 16, 0, 0);
}

// ---------------- fp32 -> bf16 conversion (fused, z-indexed) --------------
__global__ void cvt_act_kernel(const float* __restrict__ s0,
                               const float* __restrict__ s1,
                               const float* __restrict__ s2,
                               unsigned short* __restrict__ d0,
                               unsigned short* __restrict__ d1,
                               unsigned short* __restrict__ d2, int n4) {
  const float* src = (blockIdx.y == 0) ? s0 : ((blockIdx.y == 1) ? s1 : s2);
  unsigned short* dst = (blockIdx.y == 0) ? d0 : ((blockIdx.y == 1) ? d1 : d2);
  for (int i = blockIdx.x * blockDim.x + threadIdx.x; i < n4;
       i += gridDim.x * blockDim.x) {
    float4 v = reinterpret_cast<const float4*>(src)[i];
    ushort4 o;
    o.x = f2bf(v.x); o.y = f2bf(v.y); o.z = f2bf(v.z); o.w = f2bf(v.w);
    reinterpret_cast<ushort4*>(dst)[i] = o;
  }
}

__global__ void cvt_w_kernel(const float* __restrict__ s0,
                             const float* __restrict__ s1,
                             const float* __restrict__ s2,
                             const float* __restrict__ s3,
                             unsigned short* __restrict__ d0,
                             unsigned short* __restrict__ d1,
                             unsigned short* __restrict__ d2,
                             unsigned short* __restrict__ d3, int n4) {
  const int z = blockIdx.y;
  const float* src = (z == 0) ? s0 : ((z == 1) ? s1 : ((z == 2) ? s2 : s3));
  unsigned short* dst = (z == 0) ? d0 : ((z == 1) ? d1 : ((z == 2) ? d2 : d3));
  for (int i = blockIdx.x * blockDim.x + threadIdx.x; i < n4;
       i += gridDim.x * blockDim.x) {
    float4 v = reinterpret_cast<const float4*>(src)[i];
    ushort4 o;
    o.x = f2bf(v.x); o.y = f2bf(v.y); o.z = f2bf(v.z); o.w = f2bf(v.w);
    reinterpret_cast<ushort4*>(dst)[i] = o;
  }
}

// ---------------- 128x128-tile GEMM: out = A @ W^T (m97 structure) --------
// A: [M][E] bf16. W: [N=E][E] bf16 (row = out col). BK=32, 4 waves 2x2,
// global_load_lds width-16 staging, 2 barriers per K-step.
// MODE 0: Q -> Qh[B][H][S][D] * 0.125   MODE 1: K -> Kh[B][H][S][D]
// MODE 2: V -> Vt[B][H][D][S]           MODE 3: fp32 row-major out
template <int MODE>
__global__ __launch_bounds__(256) void gemm128_kernel(
    const unsigned short* __restrict__ A, const unsigned short* __restrict__ W,
    unsigned short* __restrict__ obf, float* __restrict__ of32) {
  __shared__ __align__(16) unsigned short As[128 * 32];
  __shared__ __align__(16) unsigned short Bs[128 * 32];

  const int wave = threadIdx.x >> 6;
  const int lane = threadIdx.x & 63;
  const int lr = lane & 15;
  const int lk = (lane >> 4) * 8;
  const int m0 = blockIdx.x * 128;
  const int n0 = blockIdx.y * 128;
  const int wm = (wave >> 1) * 64;
  const int wn = (wave & 1) * 64;
  const int srow = lane >> 2;        // row within 16-row staging chunk
  const int scol = (lane & 3) * 8;   // element col within BK=32

  f32x4 acc[4][4];
  const f32x4 fz = {0.f, 0.f, 0.f, 0.f};
#pragma unroll
  for (int i = 0; i < 4; ++i)
#pragma unroll
    for (int j = 0; j < 4; ++j) acc[i][j] = fz;

  for (int kk = 0; kk < E; kk += 32) {
    // stage A[128][32], B[128][32]; chunk c = 16 rows = 1KB = one wave issue
#pragma unroll
    for (int i = 0; i < 2; ++i) {
      const int c = wave * 2 + i;
      const int row = c * 16 + srow;
      gload_lds16(A + (size_t)(m0 + row) * E + kk + scol, &As[c * 512]);
      gload_lds16(W + (size_t)(n0 + row) * E + kk + scol, &Bs[c * 512]);
    }
    __syncthreads();  // drains vmcnt(0): LDS tiles ready
    short8 af[4], bw[4];
#pragma unroll
    for (int i = 0; i < 4; ++i)
      af[i] = *reinterpret_cast<const short8*>(&As[(wm + i * 16 + lr) * 32 + lk]);
#pragma unroll
    for (int j = 0; j < 4; ++j)
      bw[j] = *reinterpret_cast<const short8*>(&Bs[(wn + j * 16 + lr) * 32 + lk]);
#pragma unroll
    for (int i = 0; i < 4; ++i)
#pragma unroll
      for (int j = 0; j < 4; ++j) acc[i][j] = MFMA16(af[i], bw[j], acc[i][j]);
    __syncthreads();  // reads done before next stage overwrites
  }

  const int rbase = (lane >> 4) * 4;
#pragma unroll
  for (int i = 0; i < 4; ++i) {
#pragma unroll
    for (int j = 0; j < 4; ++j) {
      const int col = n0 + wn + j * 16 + lr;
#pragma unroll
      for (int r = 0; r < 4; ++r) {
        const int row = m0 + wm + i * 16 + rbase + r;
        const float v = acc[i][j][r];
        if (MODE == 0) {
          const int h = col >> 6, d = col & 63, b = row >> 11, s = row & (S - 1);
          obf[(((size_t)b * H + h) * S + s) * D + d] = f2bf(v * 0.125f);
        } else if (MODE == 1) {
          const int h = col >> 6, d = col & 63, b = row >> 11, s = row & (S - 1);
          obf[(((size_t)b * H + h) * S + s) * D + d] = f2bf(v);
        } else if (MODE == 2) {
          const int h = col >> 6, d = col & 63, b = row >> 11, s = row & (S - 1);
          obf[(((size_t)b * H + h) * D + d) * S + s] = f2bf(v);
        } else {
          of32[(size_t)row * E + col] = v;
        }
      }
    }
  }
}

// ---------------- flash attention (barrier-free, swizzled P) --------------
// grid: (S/64, B*H). 4 waves/block; wave owns 16 q-rows, wave-private P LDS.
// Qh pre-scaled by 1/sqrt(D). Vt is [B][H][D][S].
__global__ __launch_bounds__(256) void attn_kernel(
    const unsigned short* __restrict__ Qh, const unsigned short* __restrict__ Kh,
    const unsigned short* __restrict__ Vt, unsigned short* __restrict__ Xb) {
  __shared__ __align__(16) unsigned short Plds[4][16 * 64];

  const int wave = threadIdx.x >> 6;
  const int lane = threadIdx.x & 63;
  const int lr = lane & 15;
  const int lk = (lane >> 4) * 8;
  const int rbase = (lane >> 4) * 4;
  const int bh = blockIdx.y;
  const int q0 = blockIdx.x * 64 + wave * 16;

  const unsigned short* Qp = Qh + ((size_t)bh * S + q0) * D;
  short8 qf0 = *reinterpret_cast<const short8*>(Qp + (size_t)lr * D + lk);
  short8 qf1 = *reinterpret_cast<const short8*>(Qp + (size_t)lr * D + 32 + lk);

  const f32x4 fz = {0.f, 0.f, 0.f, 0.f};
  float mrun[4], lsum[4];
  f32x4 acc[4];
#pragma unroll
  for (int r = 0; r < 4; ++r) { mrun[r] = -3.0e38f; lsum[r] = 0.f; }
#pragma unroll
  for (int dt = 0; dt < 4; ++dt) acc[dt] = fz;

  const unsigned short* Vbase = Vt + (size_t)bh * D * S;
  unsigned short* Pw = &Plds[wave][0];

  for (int kt = 0; kt < S; kt += 64) {
    const unsigned short* Kp = Kh + ((size_t)bh * S + kt) * D;
    f32x4 sf[4];
#pragma unroll
    for (int nt = 0; nt < 4; ++nt) {
      const unsigned short* kr = Kp + (size_t)(nt * 16 + lr) * D + lk;
      short8 kf0 = *reinterpret_cast<const short8*>(kr);
      short8 kf1 = *reinterpret_cast<const short8*>(kr + 32);
      f32x4 z = fz;
      z = MFMA16(qf0, kf0, z);
      z = MFMA16(qf1, kf1, z);
      sf[nt] = z;
    }

    // V fragment loads issued early: latency hides under softmax VALU
    short8 vf0[4], vf1[4];
#pragma unroll
    for (int dt = 0; dt < 4; ++dt) {
      const unsigned short* vr = Vbase + (size_t)(dt * 16 + lr) * S + kt + lk;
      vf0[dt] = *reinterpret_cast<const short8*>(vr);
      vf1[dt] = *reinterpret_cast<const short8*>(vr + 32);
    }

    float p[4][4];
#pragma unroll
    for (int r = 0; r < 4; ++r) {
      float mx = fmaxf(fmaxf(sf[0][r], sf[1][r]), fmaxf(sf[2][r], sf[3][r]));
      mx = fmaxf(mx, __shfl_xor(mx, 1));
      mx = fmaxf(mx, __shfl_xor(mx, 2));
      mx = fmaxf(mx, __shfl_xor(mx, 4));
      mx = fmaxf(mx, __shfl_xor(mx, 8));
      const float nm = fmaxf(mrun[r], mx);
      const float fac = __expf(mrun[r] - nm);
      mrun[r] = nm;
      float rs = 0.f;
#pragma unroll
      for (int nt = 0; nt < 4; ++nt) {
        p[nt][r] = __expf(sf[nt][r] - nm);
        rs += p[nt][r];
      }
      rs += __shfl_xor(rs, 1);
      rs += __shfl_xor(rs, 2);
      rs += __shfl_xor(rs, 4);
      rs += __shfl_xor(rs, 8);
      lsum[r] = lsum[r] * fac + rs;
#pragma unroll
      for (int dt = 0; dt < 4; ++dt) acc[dt][r] *= fac;
    }

    // C/D -> A-fragment re-layout through wave-private LDS, XOR-swizzled:
    // element (row, colg) stored at row*64 + ((g ^ (row&7))*8 + (colg&7)),
    // g = colg>>3. Row-groups of 8 granules -> 2-way banks (free).
#pragma unroll
    for (int nt = 0; nt < 4; ++nt) {
#pragma unroll
      for (int r = 0; r < 4; ++r) {
        const int row = rbase + r;
        const int colg = nt * 16 + lr;
        const int g = colg >> 3;
        Pw[row * 64 + ((g ^ (row & 7)) * 8) + (colg & 7)] = f2bf(p[nt][r]);
      }
    }
    // wave-local ordering: DS pipe is in-order per wave; fence the compiler
    __builtin_amdgcn_sched_barrier(0);
    asm volatile("s_waitcnt lgkmcnt(0)" ::: "memory");
    __builtin_amdgcn_sched_barrier(0);
    const int g0 = lane >> 4;  // lk>>3
    short8 pa0 = *reinterpret_cast<const short8*>(
        &Pw[lr * 64 + ((g0 ^ (lr & 7)) * 8)]);
    short8 pa1 = *reinterpret_cast<const short8*>(
        &Pw[lr * 64 + (((g0 + 4) ^ (lr & 7)) * 8)]);
    __builtin_amdgcn_wave_barrier();  // keep reads ahead of next-iter writes

#pragma unroll
    for (int dt = 0; dt < 4; ++dt) {
      acc[dt] = MFMA16(pa0, vf0[dt], acc[dt]);
      acc[dt] = MFMA16(pa1, vf1[dt], acc[dt]);
    }
  }

  const int b = bh >> 4, h = bh & (H - 1);
#pragma unroll
  for (int r = 0; r < 4; ++r) {
    const float inv = 1.0f / lsum[r];
    const int row = q0 + rbase + r;
#pragma unroll
    for (int dt = 0; dt < 4; ++dt) {
      Xb[((size_t)b * S + row) * E + h * D + dt * 16 + lr] =
          f2bf(acc[dt][r] * inv);
    }
  }
}

extern "C" void kernel_launch(void* const* d_in, const int* in_sizes, int n_in,
                              void* d_out, int out_size, void* d_ws, size_t ws_size,
                              hipStream_t stream) {
  const float* q_f = (const float*)d_in[0];
  const float* k_f = (const float*)d_in[1];
  const float* v_f = (const float*)d_in[2];
  const float* wq_f = (const float*)d_in[3];
  const float* wk_f = (const float*)d_in[4];
  const float* wv_f = (const float*)d_in[5];
  const float* wo_f = (const float*)d_in[6];

  // workspace layout (bf16 halves): 7*NE + 4*NW elements = 64 MB
  unsigned short* xq = (unsigned short*)d_ws;
  unsigned short* xk = xq + NE;
  unsigned short* xv = xk + NE;
  unsigned short* wq = xv + NE;
  unsigned short* wk = wq + NW;
  unsigned short* wv = wk + NW;
  unsigned short* wo = wv + NW;
  unsigned short* Qh = wo + NW;
  unsigned short* Kh = Qh + NE;
  unsigned short* Vt = Kh + NE;
  unsigned short* Xb = Vt + NE;

  // 1) convert inputs + weights to bf16 (2 fused launches)
  cvt_act_kernel<<<dim3(512, 3), 256, 0, stream>>>(q_f, k_f, v_f, xq, xk, xv,
                                                   (int)(NE / 4));
  cvt_w_kernel<<<dim3(256, 4), 256, 0, stream>>>(wq_f, wk_f, wv_f, wo_f, wq, wk,
                                                 wv, wo, (int)(NW / 4));

  // 2) Q/K/V projections
  gemm128_kernel<0><<<dim3(M / 128, E / 128), 256, 0, stream>>>(xq, wq, Qh, nullptr);
  gemm128_kernel<1><<<dim3(M / 128, E / 128), 256, 0, stream>>>(xk, wk, Kh, nullptr);
  gemm128_kernel<2><<<dim3(M / 128, E / 128), 256, 0, stream>>>(xv, wv, Vt, nullptr);

  // 3) flash attention
  attn_kernel<<<dim3(S / 64, B * H), 256, 0, stream>>>(Qh, Kh, Vt, Xb);

  // 4) output projection (fp32 out)
  gemm128_kernel<3><<<dim3(M / 128, E / 128), 256, 0, stream>>>(Xb, wo, nullptr,
                                                                (float*)d_out);
}